// Round 15
// baseline (50.306 us; speedup 1.0000x reference)
//
#include <hip/hip_runtime.h>

#define N_ROWS 14400
#define M_COLS 1600
#define KDIM   256
#define GRID_X 25           // 1600 / 64  (exact)
#define GRID_Y 225          // 14400 / 64 (exact)
#define NWG    (GRID_X * GRID_Y)   // 5625

typedef __attribute__((ext_vector_type(8))) short bf16x8;
typedef __attribute__((ext_vector_type(4))) float f32x4;

__device__ __forceinline__ short f2bf(float x) {
  union { float f; unsigned u; } v; v.f = x;
  unsigned r = v.u + 0x7FFFu + ((v.u >> 16) & 1u);   // RNE to bf16
  return (short)(r >> 16);
}

__device__ __forceinline__ void gload_lds16(const void* g, void* l) {
  __builtin_amdgcn_global_load_lds(
      (const __attribute__((address_space(1))) void*)g,
      (__attribute__((address_space(3))) void*)l, 16, 0, 0);
}

// One WAVE per row; lane handles 4 consecutive floats (float4 in, short4 out).
__global__ __launch_bounds__(256) void prep_kernel(
    const float* __restrict__ logits, const float* __restrict__ embs,
    short* __restrict__ probB, short* __restrict__ embB) {
  const int row = blockIdx.x * 4 + (threadIdx.x >> 6);
  const int lane = threadIdx.x & 63;
  if (row < N_ROWS) {
    const float4 x = ((const float4*)(logits + (size_t)row * KDIM))[lane];
    float s = x.x * x.x + x.y * x.y + x.z * x.z + x.w * x.w;
#pragma unroll
    for (int o = 32; o > 0; o >>= 1) s += __shfl_xor(s, o, 64);
    const float scale = __builtin_amdgcn_rsqf(s);
    short4 o4;
    o4.x = f2bf(x.x * scale); o4.y = f2bf(x.y * scale);
    o4.z = f2bf(x.z * scale); o4.w = f2bf(x.w * scale);
    ((short4*)(probB + (size_t)row * KDIM))[lane] = o4;
  } else {
    const int r = row - N_ROWS;   // grid sized exactly, no overflow
    const float4 x = ((const float4*)(embs + (size_t)r * KDIM))[lane];
    short4 o4;
    o4.x = f2bf(x.x); o4.y = f2bf(x.y); o4.z = f2bf(x.z); o4.w = f2bf(x.w);
    ((short4*)(embB + (size_t)r * KDIM))[lane] = o4;
  }
}

// 64x64 tile GEMM (bf16 MFMA) + fused bbox-L1 + GIoU + sigmoid epilogue.
// r15 = r14 + double-buffered K-loop with ONE __syncthreads per iter
// ("r10 done right": BK=64, rolled 4-iter loop, no unroll collapse):
//   prologue STAGE(0,buf0); sync;
//   iter kt: STAGE(kt+1, buf^1) -> compute(buf) [8 ds_read + 8 MFMA] -> sync.
// The sync's vmcnt-drain lands AFTER the compute phase, so next-tile loads
// overlap ~300 cyc of MFMA/ds_read instead of being drained at issue (r14
// staged then immediately barriered). Barriers: 8 -> 5 per block.
// - acc[2][2] = 16 AGPR; 4 waves of 32x32; exact tiling (zero guards).
// - LDS 36 KB (As2/Bs2 double + boxes) -> 4 blocks/CU.
// - XOR-swizzled GEMM tiles -> 0 bank conflicts.
// - Epilogue (r14): 2 passes, per-wr 16x68 tbuf overlay, lgkm-only barriers,
//   256-B-coalesced dwordx4 NT stores (never drained mid-epilogue).
// - Bijective XCD swizzle (FETCH ~7 MB, inputs L2-resident).
// - No launch clamp (r2/r4/r10: forced VGPR<=64 always lost ~10us).
__global__ __launch_bounds__(256) void cost_kernel(
    const short* __restrict__ probB, const short* __restrict__ embB,
    const float* __restrict__ pbox, const float* __restrict__ tbox,
    float* __restrict__ out) {
  __shared__ short As2[2][64 * 64];   // 16 KB; tbuf overlays in epilogue
  __shared__ short Bs2[2][64 * 64];   // 16 KB
  __shared__ f32x4 rowcc[64], rowxy[64];   // 2 KB
  __shared__ f32x4 colcc[64], colxy[64];   // 2 KB

  const int t = threadIdx.x;
  const int lane = t & 63;
  const int wid = t >> 6;
  const int wr = wid >> 1;          // wave row 0..1 (32-row band)
  const int wc = wid & 1;           // wave col 0..1 (32-col band)

  // Bijective XCD swizzle (m204): 8 XCDs, NWG=5625 (q=703, r=1).
  const int orig = blockIdx.x;
  const int xcd = orig & 7;
  const int rem = orig >> 3;
  const int q = NWG >> 3, r = NWG & 7;
  const int wgid = (xcd < r ? xcd * (q + 1) : r * (q + 1) + (xcd - r) * q) + rem;
  const int bx = wgid % GRID_X;
  const int by = wgid / GRID_X;
  const int rowBase = by * 64;      // N (pred): always in-range (225*64)
  const int colBase = bx * 64;      // M (tgt):  always in-range (25*64)

  // Stage per-tile box data (no clamps: exact tiling).
  if (t < 64) {
    const float4 bb = ((const float4*)pbox)[rowBase + t];
    rowcc[t] = (f32x4){bb.x, bb.y, bb.z, bb.w};
    rowxy[t] = (f32x4){fmaf(-0.5f, bb.z, bb.x), fmaf(-0.5f, bb.w, bb.y),
                       fmaf(0.5f, bb.z, bb.x), fmaf(0.5f, bb.w, bb.y)};
  } else if (t < 128) {
    const int c = t - 64;
    const float4 bb = ((const float4*)tbox)[colBase + c];
    colcc[c] = (f32x4){bb.x, bb.y, bb.z, bb.w};
    colxy[c] = (f32x4){fmaf(-0.5f, bb.z, bb.x), fmaf(-0.5f, bb.w, bb.y),
                       fmaf(0.5f, bb.z, bb.x), fmaf(0.5f, bb.w, bb.y)};
  }

  f32x4 acc[2][2];
#pragma unroll
  for (int i = 0; i < 2; ++i)
#pragma unroll
    for (int j = 0; j < 2; ++j) acc[i][j] = (f32x4){0.f, 0.f, 0.f, 0.f};

  // Pre-swizzled source granule: lane l stages granule (l&7)^(l>>3); read
  // slot g^(row&7) sees linear data.
  const int swz = (lane & 7) ^ (lane >> 3);
  const int rbase = wid * 8 + (lane >> 3);   // staging row within 32-row group

#define STAGE(kt_, buf_)                                                      \
  {                                                                           \
    const int k0_ = (kt_) * 64 + swz * 8;                                     \
    _Pragma("unroll")                                                         \
    for (int i = 0; i < 2; ++i) {                                             \
      const int gr_ = rowBase + i * 32 + rbase;                               \
      gload_lds16(probB + (size_t)gr_ * KDIM + k0_,                           \
                  &As2[buf_][(i * 32 + wid * 8) * 64]);                       \
    }                                                                         \
    _Pragma("unroll")                                                         \
    for (int i = 0; i < 2; ++i) {                                             \
      const int gc_ = colBase + i * 32 + rbase;                               \
      gload_lds16(embB + (size_t)gc_ * KDIM + k0_,                            \
                  &Bs2[buf_][(i * 32 + wid * 8) * 64]);                       \
    }                                                                         \
  }

  // Prologue: stage K-tile 0 into buf 0.
  STAGE(0, 0)
  __syncthreads();

  // K-loop: 4 tiles of BK=64; one __syncthreads per iter.
  for (int kt = 0; kt < 4; ++kt) {
    const int buf = kt & 1;
    if (kt < 3) STAGE(kt + 1, buf ^ 1)
#pragma unroll
    for (int kk = 0; kk < 2; ++kk) {
      bf16x8 af[2], bfr[2];
      const int g = kk * 4 + (lane >> 4);    // 16B granule index 0..7
#pragma unroll
      for (int mi = 0; mi < 2; ++mi) {
        const int row = wr * 32 + mi * 16 + (lane & 15);
        af[mi] = *(const bf16x8*)(&As2[buf][row * 64 + ((g ^ (row & 7)) * 8)]);
      }
#pragma unroll
      for (int ni = 0; ni < 2; ++ni) {
        const int row = wc * 32 + ni * 16 + (lane & 15);
        bfr[ni] = *(const bf16x8*)(&Bs2[buf][row * 64 + ((g ^ (row & 7)) * 8)]);
      }
#pragma unroll
      for (int mi = 0; mi < 2; ++mi)
#pragma unroll
        for (int ni = 0; ni < 2; ++ni)
          acc[mi][ni] = __builtin_amdgcn_mfma_f32_16x16x32_bf16(
              af[mi], bfr[ni], acc[mi][ni], 0, 0, 0);
    }
    __syncthreads();   // drains next-tile loads (post-compute) + read-done
  }

  // Fused epilogue (r14), 2 passes over mi; tbuf overlays dead As2.
  const float LOG2E = 1.44269504f;
  const int jr = (lane >> 4) * 4;
  const int lc = lane & 15;
  float* const tb = (float*)As2 + wr * 1088;     // this wave's 16x68 buffer
  f32x4 c0v[2], c1v[2];
  float cav[2];
#pragma unroll
  for (int ni = 0; ni < 2; ++ni) {
    const int cloc = wc * 32 + ni * 16 + lc;
    c0v[ni] = colcc[cloc];
    c1v[ni] = colxy[cloc];
    cav[ni] = c0v[ni][2] * c0v[ni][3];
  }

#pragma unroll
  for (int mi = 0; mi < 2; ++mi) {
#pragma unroll
    for (int j = 0; j < 4; ++j) {
      const int rloc = wr * 32 + mi * 16 + jr + j;
      const f32x4 r0 = rowcc[rloc];
      const f32x4 r1 = rowxy[rloc];
      const float ra = r0[2] * r0[3];
#pragma unroll
      for (int ni = 0; ni < 2; ++ni) {
        const f32x4 c0 = c0v[ni], c1 = c1v[ni];
        const float cc = fmaxf(acc[mi][ni][j], 0.0f);
        const float l1 = fabsf(r0[0] - c0[0]) + fabsf(r0[1] - c0[1]) +
                         fabsf(r0[2] - c0[2]) + fabsf(r0[3] - c0[3]);
        const float iwx = fminf(r1[2], c1[2]) - fmaxf(r1[0], c1[0]);
        const float iwy = fminf(r1[3], c1[3]) - fmaxf(r1[1], c1[1]);
        const float iw = fmaxf(iwx, 0.f);
        const float ih = fmaxf(iwy, 0.f);
        const float inter = iw * ih;
        const float uni = ra + cav[ni] - inter;
        const float ex = (r0[2] + c0[2]) - iwx;
        const float ey = (r0[3] + c0[3]) - iwy;
        const float earea = ex * ey;
        const float num = fmaf(uni, uni, inter * earea);
        const float Cv = fmaf(-num, __builtin_amdgcn_rcpf(uni * earea),
                              l1 + cc + 1.0f);
        const float sg = __builtin_amdgcn_rcpf(
            1.0f + __builtin_amdgcn_exp2f(-LOG2E * Cv));
        tb[(jr + j) * 68 + wc * 32 + ni * 16 + lc] = sg;
      }
    }
    // lgkm-only block barrier: LDS writes visible, NT stores keep streaming.
    asm volatile("s_waitcnt lgkmcnt(0)" ::: "memory");
    __builtin_amdgcn_s_barrier();
    // Readback: thread t covers row t>>4 (of 16), 16-B col-group t&15,
    // from BOTH wr-buffers (global rows mi*16+r and 32+mi*16+r).
    {
      const int rch = t >> 4;                // 0..15
      const int c4 = (t & 15) * 4;           // 0..60
      const f32x4 v0 = *(const f32x4*)((float*)As2 + rch * 68 + c4);
      const f32x4 v1 = *(const f32x4*)((float*)As2 + 1088 + rch * 68 + c4);
      float* const dst = out + (size_t)(rowBase + mi * 16 + rch) * M_COLS
                         + colBase + c4;
      __builtin_nontemporal_store(v0, (f32x4*)dst);
      __builtin_nontemporal_store(v1, (f32x4*)(dst + 32 * M_COLS));
    }
    if (mi == 0) {   // protect tbuf before pass 1 overwrites it
      asm volatile("s_waitcnt lgkmcnt(0)" ::: "memory");
      __builtin_amdgcn_s_barrier();
    }
  }
#undef STAGE
}

extern "C" void kernel_launch(void* const* d_in, const int* in_sizes, int n_in,
                              void* d_out, int out_size, void* d_ws, size_t ws_size,
                              hipStream_t stream) {
  const float* logits = (const float*)d_in[0];   // [16,900,256]
  const float* pbox   = (const float*)d_in[1];   // [16,900,4]
  const float* embs   = (const float*)d_in[2];   // [1600,256]
  const float* tbox   = (const float*)d_in[3];   // [1600,4]
  float* out = (float*)d_out;                    // [16,900,1600]

  short* probB = (short*)d_ws;                         // 14400*256 bf16
  short* embB  = probB + (size_t)N_ROWS * KDIM;        // 1600*256 bf16

  prep_kernel<<<(N_ROWS + M_COLS) / 4, 256, 0, stream>>>(logits, embs, probB, embB);

  cost_kernel<<<NWG, 256, 0, stream>>>(probB, embB, pbox, tbox, out);
}

// Round 16
// 49.037 us; speedup vs baseline: 1.0259x; 1.0259x over previous
//
#include <hip/hip_runtime.h>

#define N_ROWS 14400
#define M_COLS 1600
#define KDIM   256
#define GRID_X 25           // 1600 / 64  (exact)
#define GRID_Y 225          // 14400 / 64 (exact)
#define NWG    (GRID_X * GRID_Y)   // 5625

typedef __attribute__((ext_vector_type(8))) short bf16x8;
typedef __attribute__((ext_vector_type(4))) float f32x4;

__device__ __forceinline__ short f2bf(float x) {
  union { float f; unsigned u; } v; v.f = x;
  unsigned r = v.u + 0x7FFFu + ((v.u >> 16) & 1u);   // RNE to bf16
  return (short)(r >> 16);
}

__device__ __forceinline__ void gload_lds16(const void* g, void* l) {
  __builtin_amdgcn_global_load_lds(
      (const __attribute__((address_space(1))) void*)g,
      (__attribute__((address_space(3))) void*)l, 16, 0, 0);
}

// One WAVE per row; lane handles 4 consecutive floats (float4 in, short4 out).
__global__ __launch_bounds__(256) void prep_kernel(
    const float* __restrict__ logits, const float* __restrict__ embs,
    short* __restrict__ probB, short* __restrict__ embB) {
  const int row = blockIdx.x * 4 + (threadIdx.x >> 6);
  const int lane = threadIdx.x & 63;
  if (row < N_ROWS) {
    const float4 x = ((const float4*)(logits + (size_t)row * KDIM))[lane];
    float s = x.x * x.x + x.y * x.y + x.z * x.z + x.w * x.w;
#pragma unroll
    for (int o = 32; o > 0; o >>= 1) s += __shfl_xor(s, o, 64);
    const float scale = __builtin_amdgcn_rsqf(s);
    short4 o4;
    o4.x = f2bf(x.x * scale); o4.y = f2bf(x.y * scale);
    o4.z = f2bf(x.z * scale); o4.w = f2bf(x.w * scale);
    ((short4*)(probB + (size_t)row * KDIM))[lane] = o4;
  } else {
    const int r = row - N_ROWS;   // grid sized exactly, no overflow
    const float4 x = ((const float4*)(embs + (size_t)r * KDIM))[lane];
    short4 o4;
    o4.x = f2bf(x.x); o4.y = f2bf(x.y); o4.z = f2bf(x.z); o4.w = f2bf(x.w);
    ((short4*)(embB + (size_t)r * KDIM))[lane] = o4;
  }
}

// 64x64 tile GEMM (bf16 MFMA) + fused bbox-L1 + GIoU + sigmoid epilogue.
// r16 = r14 (best, 47.5us) with a SINGLE-PASS epilogue:
// - tbuf = full 64x64 f32 (16 KB) overlaying dead As+Bs; writes XOR-swizzled
//   col' = col ^ (((row>>2)&3)<<4) -> 2-way banks on write, conflict-free
//   on read (per-wave XOR value uniform), f32x4 alignment preserved.
// - Epilogue barriers: 3 -> 1 (one lgkm-only barrier between write & read).
//   All 16 KB of NT stores stream in one burst, never drained mid-epilogue.
// - K-loop/GEMM byte-identical to r14 (4 pipelining attempts r8/r10/r12/r15
//   ALL lost to this naive loop; do not touch it).
// - acc[2][2] = 16 AGPR; exact 64-tiling (zero guards); LDS 20 KB;
//   XOR-swizzled GEMM tiles -> 0 conflicts; bijective XCD swizzle;
//   no launch clamp (r2/r4/r10: forced VGPR<=64 always lost ~10us).
__global__ __launch_bounds__(256) void cost_kernel(
    const short* __restrict__ probB, const short* __restrict__ embB,
    const float* __restrict__ pbox, const float* __restrict__ tbox,
    float* __restrict__ out) {
  __shared__ short AB[2][64 * 64];  // As=AB[0], Bs=AB[1]; tbuf overlays both
  __shared__ f32x4 rowcc[64], rowxy[64];   // 2 KB
  __shared__ f32x4 colcc[64], colxy[64];   // 2 KB
  short* const As = AB[0];
  short* const Bs = AB[1];
  float* const tbuf = (float*)AB;   // [64][64] f32, XOR-swizzled cols

  const int t = threadIdx.x;
  const int lane = t & 63;
  const int wid = t >> 6;
  const int wr = wid >> 1;          // wave row 0..1 (32-row band)
  const int wc = wid & 1;           // wave col 0..1 (32-col band)

  // Bijective XCD swizzle (m204): 8 XCDs, NWG=5625 (q=703, r=1).
  const int orig = blockIdx.x;
  const int xcd = orig & 7;
  const int rem = orig >> 3;
  const int q = NWG >> 3, r = NWG & 7;
  const int wgid = (xcd < r ? xcd * (q + 1) : r * (q + 1) + (xcd - r) * q) + rem;
  const int bx = wgid % GRID_X;
  const int by = wgid / GRID_X;
  const int rowBase = by * 64;      // N (pred): always in-range (225*64)
  const int colBase = bx * 64;      // M (tgt):  always in-range (25*64)

  // Stage per-tile box data (no clamps: exact tiling).
  if (t < 64) {
    const float4 bb = ((const float4*)pbox)[rowBase + t];
    rowcc[t] = (f32x4){bb.x, bb.y, bb.z, bb.w};
    rowxy[t] = (f32x4){fmaf(-0.5f, bb.z, bb.x), fmaf(-0.5f, bb.w, bb.y),
                       fmaf(0.5f, bb.z, bb.x), fmaf(0.5f, bb.w, bb.y)};
  } else if (t < 128) {
    const int c = t - 64;
    const float4 bb = ((const float4*)tbox)[colBase + c];
    colcc[c] = (f32x4){bb.x, bb.y, bb.z, bb.w};
    colxy[c] = (f32x4){fmaf(-0.5f, bb.z, bb.x), fmaf(-0.5f, bb.w, bb.y),
                       fmaf(0.5f, bb.z, bb.x), fmaf(0.5f, bb.w, bb.y)};
  }

  f32x4 acc[2][2];
#pragma unroll
  for (int i = 0; i < 2; ++i)
#pragma unroll
    for (int j = 0; j < 2; ++j) acc[i][j] = (f32x4){0.f, 0.f, 0.f, 0.f};

  // Pre-swizzled source granule: lane l stages granule (l&7)^(l>>3); read
  // slot g^(row&7) sees linear data.
  const int swz = (lane & 7) ^ (lane >> 3);
  const int rbase = wid * 8 + (lane >> 3);   // staging row within 32-row group

  // K-loop: 4 tiles of BK=64 (r14 verbatim).
  for (int kt = 0; kt < 4; ++kt) {
    const int k0 = kt * 64 + swz * 8;
#pragma unroll
    for (int i = 0; i < 2; ++i) {            // A: 64 rows
      const int gr = rowBase + i * 32 + rbase;
      gload_lds16(probB + (size_t)gr * KDIM + k0, As + (i * 32 + wid * 8) * 64);
    }
#pragma unroll
    for (int i = 0; i < 2; ++i) {            // B: 64 rows (cols)
      const int gc = colBase + i * 32 + rbase;
      gload_lds16(embB + (size_t)gc * KDIM + k0, Bs + (i * 32 + wid * 8) * 64);
    }
    __syncthreads();
#pragma unroll
    for (int kk = 0; kk < 2; ++kk) {
      bf16x8 af[2], bfr[2];
      const int g = kk * 4 + (lane >> 4);    // 16B granule index 0..7
#pragma unroll
      for (int mi = 0; mi < 2; ++mi) {
        const int row = wr * 32 + mi * 16 + (lane & 15);
        af[mi] = *(const bf16x8*)(As + row * 64 + ((g ^ (row & 7)) * 8));
      }
#pragma unroll
      for (int ni = 0; ni < 2; ++ni) {
        const int row = wc * 32 + ni * 16 + (lane & 15);
        bfr[ni] = *(const bf16x8*)(Bs + row * 64 + ((g ^ (row & 7)) * 8));
      }
#pragma unroll
      for (int mi = 0; mi < 2; ++mi)
#pragma unroll
        for (int ni = 0; ni < 2; ++ni)
          acc[mi][ni] = __builtin_amdgcn_mfma_f32_16x16x32_bf16(
              af[mi], bfr[ni], acc[mi][ni], 0, 0, 0);
    }
    __syncthreads();   // last one also protects the tbuf overlay
  }

  // Single-pass fused epilogue: all 16 outputs -> swizzled tbuf -> ONE
  // lgkm barrier -> 4 coalesced readback+NT-store rounds.
  const float LOG2E = 1.44269504f;
  const int jr = (lane >> 4) * 4;
  const int lc = lane & 15;
  f32x4 c0v[2], c1v[2];
  float cav[2];
#pragma unroll
  for (int ni = 0; ni < 2; ++ni) {
    const int cloc = wc * 32 + ni * 16 + lc;
    c0v[ni] = colcc[cloc];
    c1v[ni] = colxy[cloc];
    cav[ni] = c0v[ni][2] * c0v[ni][3];
  }

#pragma unroll
  for (int mi = 0; mi < 2; ++mi) {
#pragma unroll
    for (int j = 0; j < 4; ++j) {
      const int row = wr * 32 + mi * 16 + jr + j;
      const f32x4 r0 = rowcc[row];
      const f32x4 r1 = rowxy[row];
      const float ra = r0[2] * r0[3];
      const int cswz = ((row >> 2) & 3) << 4;   // col XOR for this row
#pragma unroll
      for (int ni = 0; ni < 2; ++ni) {
        const f32x4 c0 = c0v[ni], c1 = c1v[ni];
        const float cc = fmaxf(acc[mi][ni][j], 0.0f);
        const float l1 = fabsf(r0[0] - c0[0]) + fabsf(r0[1] - c0[1]) +
                         fabsf(r0[2] - c0[2]) + fabsf(r0[3] - c0[3]);
        const float iwx = fminf(r1[2], c1[2]) - fmaxf(r1[0], c1[0]);
        const float iwy = fminf(r1[3], c1[3]) - fmaxf(r1[1], c1[1]);
        const float iw = fmaxf(iwx, 0.f);
        const float ih = fmaxf(iwy, 0.f);
        const float inter = iw * ih;
        const float uni = ra + cav[ni] - inter;
        const float ex = (r0[2] + c0[2]) - iwx;
        const float ey = (r0[3] + c0[3]) - iwy;
        const float earea = ex * ey;
        const float num = fmaf(uni, uni, inter * earea);
        const float Cv = fmaf(-num, __builtin_amdgcn_rcpf(uni * earea),
                              l1 + cc + 1.0f);
        const float sg = __builtin_amdgcn_rcpf(
            1.0f + __builtin_amdgcn_exp2f(-LOG2E * Cv));
        const int col = wc * 32 + ni * 16 + lc;
        tbuf[row * 64 + (col ^ cswz)] = sg;
      }
    }
  }
  // ONE lgkm-only block barrier: LDS writes visible, NT stores never drained.
  asm volatile("s_waitcnt lgkmcnt(0)" ::: "memory");
  __builtin_amdgcn_s_barrier();
  // Readback: 4 rounds; round rr: thread t -> row rr*16 + (t>>4), 16-B col
  // group (t&15). Per-wave XOR value is uniform -> conflict-free; stores are
  // 256-B-coalesced NT dwordx4.
#pragma unroll
  for (int rr = 0; rr < 4; ++rr) {
    const int row = rr * 16 + (t >> 4);
    const int col = (t & 15) * 4;
    const int cswz = ((row >> 2) & 3) << 4;
    const f32x4 v = *(const f32x4*)(tbuf + row * 64 + (col ^ cswz));
    __builtin_nontemporal_store(
        v, (f32x4*)(out + (size_t)(rowBase + row) * M_COLS + colBase + col));
  }
}

extern "C" void kernel_launch(void* const* d_in, const int* in_sizes, int n_in,
                              void* d_out, int out_size, void* d_ws, size_t ws_size,
                              hipStream_t stream) {
  const float* logits = (const float*)d_in[0];   // [16,900,256]
  const float* pbox   = (const float*)d_in[1];   // [16,900,4]
  const float* embs   = (const float*)d_in[2];   // [1600,256]
  const float* tbox   = (const float*)d_in[3];   // [1600,4]
  float* out = (float*)d_out;                    // [16,900,1600]

  short* probB = (short*)d_ws;                         // 14400*256 bf16
  short* embB  = probB + (size_t)N_ROWS * KDIM;        // 1600*256 bf16

  prep_kernel<<<(N_ROWS + M_COLS) / 4, 256, 0, stream>>>(logits, embs, probB, embB);

  cost_kernel<<<NWG, 256, 0, stream>>>(probB, embB, pbox, tbox, out);
}